// Round 13
// baseline (1632.987 us; speedup 1.0000x reference)
//
#include <hip/hip_runtime.h>
#include <cmath>

// EVRP solver rollout — one block per batch element, 128-step decode on-device.
// PRNG: JAX threefry2x32 partitionable scheme (verified). Discrete state path
// (fuel/time/demand/mask) is bit-exact vs jnp f32; logit path is analog.
// R13 = R9 (748us best) + unroll-2 cap on E's LDS-indexed loop ONLY (trims
// float4 over-hoisting -> scratch spill). Private-array loops stay fully
// unrolled (R10/R11 lesson: partial unroll demotes them to scratch, 4.3GB).
// Gumbel computed in-kernel (R12 lesson: pre-kernel adds 67MB traffic, -19us).
#define BSZ 256
#define SEQN 256
#define HD 128
#define NEGV -1000000000.0f
#define TINYF 1.17549435e-38f
#define LOG2E 1.4426950408889634f
#define LN2F 0.6931471805599453f
#define K2L 2.885390081777927f

typedef float v2f __attribute__((ext_vector_type(2)));

static __device__ __forceinline__ v2f mk2(float a, float b) {
  v2f r; r.x = a; r.y = b; return r;
}
static __device__ __forceinline__ v2f fma2(v2f a, v2f b, v2f c) {
  return __builtin_elementwise_fma(a, b, c);
}

// DPP lane ops (VALU pipe — not LDS). quad_perm 0xB1=xor1, 0x4E=xor2, 0x1B=xor3.
#define DPPF(x, c) __int_as_float(__builtin_amdgcn_update_dpp(0, __float_as_int(x), (c), 0xF, 0xF, true))
#define DPPI(x, c) __builtin_amdgcn_update_dpp(0, (x), (c), 0xF, 0xF, true)
#define SWZF(x, p) __int_as_float(__builtin_amdgcn_ds_swizzle(__float_as_int(x), (p)))

static __device__ __forceinline__ void tf2x32(unsigned k0, unsigned k1,
                                              unsigned x0, unsigned x1,
                                              unsigned &o0, unsigned &o1) {
  unsigned ks2 = k0 ^ k1 ^ 0x1BD11BDAu;
#define TFR(r) { x0 += x1; x1 = (x1 << (r)) | (x1 >> (32 - (r))); x1 ^= x0; }
  x0 += k0; x1 += k1;
  TFR(13) TFR(15) TFR(26) TFR(6)
  x0 += k1; x1 += ks2 + 1u;
  TFR(17) TFR(29) TFR(16) TFR(24)
  x0 += ks2; x1 += k0 + 2u;
  TFR(13) TFR(15) TFR(26) TFR(6)
  x0 += k0; x1 += k1 + 3u;
  TFR(17) TFR(29) TFR(16) TFR(24)
  x0 += k1; x1 += ks2 + 4u;
  TFR(13) TFR(15) TFR(26) TFR(6)
  x0 += ks2; x1 += k0 + 5u;
#undef TFR
  o0 = x0; o1 = x1;
}

static __device__ __forceinline__ float fast_tanh(float x) {
  float y = __fmul_rn(x, K2L);
  float ay = __int_as_float(__float_as_int(y) | 0x80000000u); // -|y|
  float q = __builtin_amdgcn_exp2f(ay);
  float r = __fmul_rn(__fsub_rn(1.0f, q),
                      __builtin_amdgcn_rcpf(__fadd_rn(1.0f, q)));
  unsigned sgn = (unsigned)__float_as_int(x) & 0x80000000u;
  return __int_as_float(__float_as_int(r) | sgn);
}

static __device__ __forceinline__ float fast_sig(float x) {
  float q = __builtin_amdgcn_exp2f(__fmul_rn(x, -LOG2E));
  return __builtin_amdgcn_rcpf(__fadd_rn(1.0f, q));
}

static __device__ __forceinline__ float fast_ln(float x) {
  return __fmul_rn(__builtin_amdgcn_logf(x), LN2F);
}

__global__ __launch_bounds__(512, 2) void evrp_kernel(
    const float* __restrict__ statc, const float* __restrict__ dyn,
    const float* __restrict__ dist,  const float* __restrict__ W_s,
    const float* __restrict__ b_s,   const float* __restrict__ W_d,
    const float* __restrict__ b_d,   const float* __restrict__ W_i,
    const float* __restrict__ W_h,   const float* __restrict__ b_i,
    const float* __restrict__ b_h,   const float* __restrict__ W_att,
    const float* __restrict__ v_att, const float* __restrict__ W_c,
    const float* __restrict__ b_c,   const int* __restrict__ steps_p,
    float* __restrict__ out) {
  const int b = blockIdx.x;
  const int tid = threadIdx.x;
  const int T = steps_p[0];
  const int lane = tid & 63;
  const int wv = tid >> 6;
  const int s = tid >> 1, hf = tid & 1;      // E/FG mapping
  const int cq = tid >> 2, g = tid & 3;      // AB/C mapping

  extern __shared__ __align__(16) float4 Pdyn[];   // sP: [16 chunks][512] = 128KB

  __shared__ __align__(16) float  B0a[HD], B1a[HD], A2a[HD];
  __shared__ __align__(16) float  Ct[HD], Vt[HD];   // Ct holds sC per step
  __shared__ __align__(16) float  hstm[HD], hlm[HD], wc2v[HD];
  __shared__ __align__(16) float  A0a[HD], A1a[HD], D0a[HD];
  __shared__ __align__(16) float  C0a[HD], C1a[HD], C2a[HD], bca[HD];
  __shared__ __align__(16) float2 xy2[SEQN];
  __shared__ __align__(16) float  drowX[SEQN];
  __shared__ __align__(16) unsigned kAs[256], kBs[256];
  __shared__ __align__(16) float ws0[HD], ws1[HD], bsv[HD];
  __shared__ __align__(16) float wd0[HD], wd1[HD], wd2[HD], bdv[HD];
  __shared__ __align__(16) float2 wredA[8];   // {av, (float)ai}
  __shared__ __align__(16) float4 wredB[8];   // {S, px, py, -}

  const float* distb = dist + (size_t)b * SEQN * SEQN;

  // ---------------- prologue: loads ----------------
  if (tid < HD) {
    ws0[tid] = W_s[2 * tid]; ws1[tid] = W_s[2 * tid + 1]; bsv[tid] = b_s[tid];
    wd0[tid] = W_d[3 * tid]; wd1[tid] = W_d[3 * tid + 1]; wd2[tid] = W_d[3 * tid + 2];
    bdv[tid] = b_d[tid]; bca[tid] = b_c[tid];
    hstm[tid] = 0.0f;
  }
  float xreg = statc[b * 2 * SEQN + s];
  float yreg = statc[b * 2 * SEQN + SEQN + s];
  float demreg = dyn[b * 3 * SEQN + 2 * SEQN + s];
  float d2dR = distb[(size_t)s * SEQN];
  float dbaR;
  {
    float d10 = distb[1 * SEQN + 0], d20 = distb[2 * SEQN + 0], d30 = distb[3 * SEQN + 0];
    float d1s = distb[1 * SEQN + s], d2s = distb[2 * SEQN + s], d3s = distb[3 * SEQN + s];
    float m = fminf(fminf(__fadd_rn(d10, d1s), __fadd_rn(d20, d2s)), __fadd_rn(d30, d3s));
    dbaR = (s == 0) ? 0.0f : m;
  }
  float dnextR = distb[s];       // row 0 — fills drowX at E_0
  if (hf == 0) xy2[s] = make_float2(xreg, yreg);
  float fuelR = dyn[b * 3 * SEQN + 0];
  float timeR = dyn[b * 3 * SEQN + SEQN + 0];
  float cstR = 0.0f;
  int niR = 0;
  for (int tt = tid; tt < 256; tt += 512) {
    unsigned a0, a1; tf2x32(0u, 1u, 0u, (unsigned)tt, a0, a1);
    kAs[tt] = a0; kBs[tt] = a1;
  }
  __syncthreads();

  // ---------------- prologue: folds + register weights ----------------
  if (tid < HD) {
    int k = tid;
    const float* row = W_att + (size_t)k * 384;
    float B0 = 0, B1 = 0, B2 = 0, A0 = 0, A1 = 0, A2 = 0, A3 = 0;
    for (int c = 0; c < HD; ++c) {
      float w1 = row[c], w2 = row[128 + c];
      B0 = fmaf(w1, ws0[c], B0); B1 = fmaf(w1, ws1[c], B1); B2 = fmaf(w1, bsv[c], B2);
      A0 = fmaf(w2, wd0[c], A0); A1 = fmaf(w2, wd1[c], A1);
      A2 = fmaf(w2, wd2[c], A2); A3 = fmaf(w2, bdv[c], A3);
    }
    B0a[k] = B0; B1a[k] = B1; A2a[k] = A2; Vt[k] = v_att[k];
    A0a[k] = A0; A1a[k] = A1; D0a[k] = __fadd_rn(B2, A3);
  } else if (tid < 2 * HD) {
    int o = tid - HD;
    const float* row = W_c + (size_t)o * 256;
    float C0 = 0, C1 = 0, C2 = 0;
    for (int c = 0; c < HD; ++c) {
      float w = row[c];
      C0 = fmaf(w, ws0[c], C0); C1 = fmaf(w, ws1[c], C1); C2 = fmaf(w, bsv[c], C2);
    }
    C0a[o] = C0; C1a[o] = C1; C2a[o] = C2;
  }
  float gp0 = 0, gp1 = 0, gp2 = 0, gpw;
  {
    int j = g * HD + cq;
    const float* row = W_i + (size_t)j * HD;
    for (int c = 0; c < HD; ++c) {
      float w = row[c];
      gp0 = fmaf(w, ws0[c], gp0); gp1 = fmaf(w, ws1[c], gp1); gp2 = fmaf(w, bsv[c], gp2);
    }
    gpw = __fadd_rn(b_i[j], b_h[j]);
  }
  // register-resident weights — loaded once, then made OPAQUE. All loops that
  // index these arrays are FULLY unrolled (compile-time indices only).
  v2f whreg2[HD / 2];
  {
    int j = g * HD + cq;
#pragma unroll
    for (int c2 = 0; c2 < HD / 2; ++c2)
      whreg2[c2] = *(const v2f*)(&W_h[(size_t)j * HD + 2 * c2]);
  }
  v2f wah2[16], wc22[16];
#pragma unroll
  for (int i = 0; i < 16; ++i) {
    wah2[i] = *(const v2f*)(&W_att[(size_t)cq * 384 + 256 + g * 32 + 2 * i]);
    wc22[i] = *(const v2f*)(&W_c[(size_t)cq * 256 + HD + g * 32 + 2 * i]);
  }
#pragma unroll
  for (int c = 0; c < HD / 2; c += 2)
    asm volatile("" : "+v"(whreg2[c]), "+v"(whreg2[c + 1]));
#pragma unroll
  for (int i = 0; i < 16; i += 2) {
    asm volatile("" : "+v"(wah2[i]), "+v"(wah2[i + 1]));
    asm volatile("" : "+v"(wc22[i]), "+v"(wc22[i + 1]));
  }
  __syncthreads();

  // ---------------- prologue: fill sP[s][k] = exp2(K2L*P) (rollout-constant)
  for (int idx = tid; idx < SEQN * HD; idx += 512) {
    int ss = idx >> 7, k = idx & 127;
    float2 pxy = xy2[ss];
    float dm = dyn[b * 3 * SEQN + 2 * SEQN + ss];
    float pv = fmaf(B0a[k], pxy.x, fmaf(B1a[k], pxy.y, __fmul_rn(A2a[k], dm)));
    ((float*)Pdyn)[(((k >> 2) & 15) << 11) + ((ss * 2 + (k >> 6)) << 2) + (k & 3)] =
        __builtin_amdgcn_exp2f(__fmul_rn(pv, K2L));
  }
  // Vsum = sum of v_att (folds the "+1" of tanh identity); uniform all threads
  float Vsum = 0.0f;
#pragma unroll
  for (int i = 0; i < 32; ++i) {
    float4 v4 = ((const float4*)Vt)[i];
    Vsum = __fadd_rn(Vsum, __fadd_rn(__fadd_rn(v4.x, v4.y), __fadd_rn(v4.z, v4.w)));
  }
  __syncthreads();

  float decxR = xy2[0].x, decyR = xy2[0].y;

  float* out_probs = out;
  float* out_tours = out + (size_t)BSZ * T * SEQN;
  float* out_logps = out_tours + (size_t)BSZ * T;

  const float4* Pp = Pdyn + (s * 2 + hf);   // + chunk*512
  const float* CtH = Ct + hf * 64;
  const float* VtH = Vt + hf * 64;

  float prevPr = 0.0f, prevLp = 0.0f;
  int prevNi = 0;

  // ---------------- decode loop (4 barriers/step) ----------------
  for (int t = 0; t < T; ++t) {
    // ---- top: prev-step stores + this step's distance-row gather ----
    if (t > 0) {
      if (hf == 0) out_probs[((size_t)b * T + (t - 1)) * SEQN + s] = prevPr;
      if (s == prevNi && hf == 0) {
        out_tours[(size_t)b * T + (t - 1)] = (float)prevNi;
        out_logps[(size_t)b * T + (t - 1)] = prevLp;
      }
      dnextR = distb[(size_t)niR * SEQN + s];
    }
    // ---- AB: gates + LSTM via quad DPP exchange; 4 acc chains ---- [(cq,g)]
    {
      v2f mA0 = mk2(0.f, 0.f), mB0 = mk2(0.f, 0.f);
      v2f mA1 = mk2(0.f, 0.f), mB1 = mk2(0.f, 0.f);
      const float4* h4 = (const float4*)hstm;
#pragma unroll
      for (int c8 = 0; c8 < HD / 8; ++c8) {
        float4 h0 = h4[2 * c8], h1 = h4[2 * c8 + 1];
        mA0 = fma2(whreg2[4 * c8 + 0], mk2(h0.x, h0.y), mA0);
        mB0 = fma2(whreg2[4 * c8 + 1], mk2(h0.z, h0.w), mB0);
        mA1 = fma2(whreg2[4 * c8 + 2], mk2(h1.x, h1.y), mA1);
        mB1 = fma2(whreg2[4 * c8 + 3], mk2(h1.z, h1.w), mB1);
      }
      float md = fmaf(gp0, decxR, fmaf(gp1, decyR, gp2));
      float mh = __fadd_rn(
          __fadd_rn(__fadd_rn(mA0.x, mA0.y), __fadd_rn(mB0.x, mB0.y)),
          __fadd_rn(__fadd_rn(mA1.x, mA1.y), __fadd_rn(mB1.x, mB1.y)));
      float V = __fadd_rn(__fadd_rn(md, mh), gpw);
      float sg = fast_sig(V), th = fast_tanh(V);
      float q = (g == 2) ? th : sg;
      float u1 = DPPF(q, 0xB1);
      float u2 = DPPF(q, 0x4E);
      float u3 = DPPF(q, 0x1B);
      float qi = (g == 0) ? q  : (g == 1) ? u1 : (g == 2) ? u2 : u3;
      float qf = (g == 0) ? u1 : (g == 1) ? q  : (g == 2) ? u3 : u2;
      float qg = (g == 0) ? u2 : (g == 1) ? u3 : (g == 2) ? q  : u1;
      float qo = (g == 0) ? u3 : (g == 1) ? u2 : (g == 2) ? u1 : q;
      float cn = __fadd_rn(__fmul_rn(qf, cstR), __fmul_rn(qi, qg));
      cstR = cn;
      float hv = __fmul_rn(qo, fast_tanh(cn));
      if (g == 0) hlm[(cq & 96) | ((cq & 31) ^ ((cq >> 5) << 3))] = hv;
    }
    __syncthreads();                               // b1
    // ---- C: W_att_h@h, W_c2@h; quad DPP reduce; write sC into Ct ---- [(cq,g)]
    {
      v2f pwA = mk2(0.f, 0.f), pwB = mk2(0.f, 0.f);
      v2f pcA = mk2(0.f, 0.f), pcB = mk2(0.f, 0.f);
      const float4* hl4 = (const float4*)hlm;
#pragma unroll
      for (int l4 = 0; l4 < 8; ++l4) {
        float4 hh = hl4[(g << 3) + (l4 ^ (g << 1))];   // XOR-swizzled, conflict-free
        v2f hA = mk2(hh.x, hh.y), hB = mk2(hh.z, hh.w);
        pwA = fma2(wah2[2 * l4],     hA, pwA);
        pwB = fma2(wah2[2 * l4 + 1], hB, pwB);
        pcA = fma2(wc22[2 * l4],     hA, pcA);
        pcB = fma2(wc22[2 * l4 + 1], hB, pcB);
      }
      float pw = __fadd_rn(__fadd_rn(pwA.x, pwA.y), __fadd_rn(pwB.x, pwB.y));
      float pc = __fadd_rn(__fadd_rn(pcA.x, pcA.y), __fadd_rn(pcB.x, pcB.y));
      pw = __fadd_rn(pw, DPPF(pw, 0xB1));
      pc = __fadd_rn(pc, DPPF(pc, 0xB1));
      pw = __fadd_rn(pw, DPPF(pw, 0x4E));
      pc = __fadd_rn(pc, DPPF(pc, 0x4E));
      if (g == 0) {
        wc2v[cq] = pc;
        float Ck = fmaf(A0a[cq], fuelR, fmaf(A1a[cq], timeR, __fadd_rn(D0a[cq], pw)));
        Ct[cq] = __builtin_amdgcn_exp2f(__fmul_rn(Ck, K2L));   // sC
      }
    }
    __syncthreads();                               // b2
    // ---- E: mask, drow fill, rcp loop (no exp), gumbel, DPP-reduce ----
    float pe, lg;
    if (hf == 0) drowX[s] = dnextR;   // row of node niR (prev step's pick)
    bool mk;
    if (t == 0) mk = true;
    else {
      bool fok = fuelR >= __fmul_rn(0.2f, __fadd_rn(dnextR, dbaR));
      bool tok = timeR >= __fdiv_rn(__fadd_rn(dnextR, d2dR), 60.0f);
      bool cust = (demreg > 0.0f) && fok && tok;
      mk = (s <= 3) ? (s != niR) : cust;
      if (s == 0) mk = true;
    }
    {
      unsigned rb;
      { unsigned o0, o1; tf2x32(kAs[t], kBs[t], 0u, (unsigned)(b * SEQN + s), o0, o1); rb = o0 ^ o1; }
      float f = __uint_as_float((rb >> 9) | 0x3f800000u) - 1.0f;
      float u = fmaxf(TINYF, __fadd_rn(f, TINYF));
      float gmb = -fast_ln(-fast_ln(u));
      const v2f one2 = mk2(1.0f, 1.0f);
      v2f a0 = mk2(0.f, 0.f), a1 = mk2(0.f, 0.f);
      v2f a2 = mk2(0.f, 0.f), a3 = mk2(0.f, 0.f);
      // unroll 2 is SAFE here: loop indexes only LDS pointers (no private
      // arrays) — caps in-flight float4 hoisting that spilled in R9.
#pragma unroll 2
      for (int i = 0; i < 8; ++i) {
        // even group 2i → chains a0,a1; odd group 2i+1 → chains a2,a3
        float4 pv0 = Pp[(2 * i) << 9];
        float4 ct0 = *(const float4*)(CtH + 8 * i);
        float4 vv0 = *(const float4*)(VtH + 8 * i);
        v2f sA = mk2(pv0.x, pv0.y) * mk2(ct0.x, ct0.y) + one2;
        v2f sB = mk2(pv0.z, pv0.w) * mk2(ct0.z, ct0.w) + one2;
        v2f rA, rB;
        rA.x = __builtin_amdgcn_rcpf(sA.x); rA.y = __builtin_amdgcn_rcpf(sA.y);
        rB.x = __builtin_amdgcn_rcpf(sB.x); rB.y = __builtin_amdgcn_rcpf(sB.y);
        a0 = fma2(mk2(vv0.x, vv0.y), rA, a0);
        a1 = fma2(mk2(vv0.z, vv0.w), rB, a1);
        float4 pv1 = Pp[(2 * i + 1) << 9];
        float4 ct1 = *(const float4*)(CtH + 8 * i + 4);
        float4 vv1 = *(const float4*)(VtH + 8 * i + 4);
        v2f sC = mk2(pv1.x, pv1.y) * mk2(ct1.x, ct1.y) + one2;
        v2f sD = mk2(pv1.z, pv1.w) * mk2(ct1.z, ct1.w) + one2;
        v2f rC, rD;
        rC.x = __builtin_amdgcn_rcpf(sC.x); rC.y = __builtin_amdgcn_rcpf(sC.y);
        rD.x = __builtin_amdgcn_rcpf(sD.x); rD.y = __builtin_amdgcn_rcpf(sD.y);
        a2 = fma2(mk2(vv1.x, vv1.y), rC, a2);
        a3 = fma2(mk2(vv1.z, vv1.w), rD, a3);
      }
      v2f t01 = a0 + a1, t23 = a2 + a3;
      v2f tt = t01 + t23;
      float part = __fadd_rn(tt.x, tt.y);
      float tot = __fadd_rn(part, DPPF(part, 0xB1));   // both halves
      float e = fmaf(-2.0f, tot, Vsum);                // Σv·tanh = Σv − 2Σv/(s+1)
      lg = mk ? e : NEGV;
      pe = __builtin_amdgcn_exp2f(__fmul_rn(lg, LOG2E));
      float sc = __fadd_rn(gmb, lg);
      float av = sc; int ai = s;
      float S = pe, px = __fmul_rn(pe, xreg), py = __fmul_rn(pe, yreg);
      {
        float ov = DPPF(av, 0x4E); int oi = DPPI(ai, 0x4E);
        if (ov > av || (ov == av && oi < ai)) { av = ov; ai = oi; }
        S  = __fadd_rn(S,  DPPF(S,  0x4E));
        px = __fadd_rn(px, DPPF(px, 0x4E));
        py = __fadd_rn(py, DPPF(py, 0x4E));
      }
      {
        float ov = DPPF(av, 0x124); int oi = DPPI(ai, 0x124);
        if (ov > av || (ov == av && oi < ai)) { av = ov; ai = oi; }
        S  = __fadd_rn(S,  DPPF(S,  0x124));
        px = __fadd_rn(px, DPPF(px, 0x124));
        py = __fadd_rn(py, DPPF(py, 0x124));
      }
      {
        float ov = DPPF(av, 0x128); int oi = DPPI(ai, 0x128);
        if (ov > av || (ov == av && oi < ai)) { av = ov; ai = oi; }
        S  = __fadd_rn(S,  DPPF(S,  0x128));
        px = __fadd_rn(px, DPPF(px, 0x128));
        py = __fadd_rn(py, DPPF(py, 0x128));
      }
      {
        float ov = SWZF(av, 0x401F); int oi = __builtin_amdgcn_ds_swizzle(ai, 0x401F);
        if (ov > av || (ov == av && oi < ai)) { av = ov; ai = oi; }
        S  = __fadd_rn(S,  SWZF(S,  0x401F));
        px = __fadd_rn(px, SWZF(px, 0x401F));
        py = __fadd_rn(py, SWZF(py, 0x401F));
      }
      {
        float ov = __shfl_xor(av, 32, 64); int oi = __shfl_xor(ai, 32, 64);
        if (ov > av || (ov == av && oi < ai)) { av = ov; ai = oi; }
        S  = __fadd_rn(S,  __shfl_xor(S,  32, 64));
        px = __fadd_rn(px, __shfl_xor(px, 32, 64));
        py = __fadd_rn(py, __shfl_xor(py, 32, 64));
      }
      if (lane == 0) {
        wredA[wv] = make_float2(av, (float)ai);
        wredB[wv] = make_float4(S, px, py, 0.0f);
      }
    }
    __syncthreads();                               // b3
    // ---- FG: packed final combine, state update, h_new ----
    {
      float2 a0c = wredA[0];
      float bv = a0c.x; int bi = (int)a0c.y;
#pragma unroll
      for (int w = 1; w < 8; ++w) {
        float2 aw = wredA[w];
        if (aw.x > bv) { bv = aw.x; bi = (int)aw.y; }
      }
      int ni = bi;
      float4 b0 = wredB[0];
      float S = b0.x, px = b0.y, py = b0.z;
#pragma unroll
      for (int w = 1; w < 8; ++w) {
        float4 bw = wredB[w];
        S = __fadd_rn(S, bw.x); px = __fadd_rn(px, bw.y); py = __fadd_rn(py, bw.z);
      }
      float dis = drowX[ni];
      float fl = __fsub_rn(fuelR, __fmul_rn(0.2f, dis));
      float tm = __fsub_rn(timeR, __fdiv_rn(dis, 60.0f));
      if (ni <= 3) fl = 60.0f;
      if (ni == 0) tm = 11.0f;
      fuelR = fl; timeR = tm;
      if (s == ni && ni > 3) demreg = 0.0f;
      float2 dxy = xy2[ni];
      decxR = dxy.x; decyR = dxy.y;
      prevPr = __fdiv_rn(pe, S);
      prevLp = __fsub_rn(lg, fast_ln(S));
      prevNi = ni;
      if (tid < HD) {
        float cx = __fdiv_rn(px, S), cy = __fdiv_rn(py, S);
        float ctxd = fmaf(C0a[tid], cx, fmaf(C1a[tid], cy, C2a[tid]));
        float val = __fadd_rn(__fadd_rn(ctxd, wc2v[tid]), bca[tid]);
        hstm[tid] = fast_tanh(val);
      }
      niR = ni;
    }
    __syncthreads();                               // b4
  }
  // final step's outputs
  if (hf == 0) out_probs[((size_t)b * T + (T - 1)) * SEQN + s] = prevPr;
  if (s == prevNi && hf == 0) {
    out_tours[(size_t)b * T + (T - 1)] = (float)prevNi;
    out_logps[(size_t)b * T + (T - 1)] = prevLp;
  }
}

extern "C" void kernel_launch(void* const* d_in, const int* in_sizes, int n_in,
                              void* d_out, int out_size, void* d_ws, size_t ws_size,
                              hipStream_t stream) {
  (void)in_sizes; (void)n_in; (void)out_size; (void)d_ws; (void)ws_size;
  (void)hipFuncSetAttribute((const void*)evrp_kernel,
                            hipFuncAttributeMaxDynamicSharedMemorySize,
                            SEQN * HD * 4);
  evrp_kernel<<<dim3(BSZ), dim3(512), SEQN * HD * 4, stream>>>(
      (const float*)d_in[0],  (const float*)d_in[1],  (const float*)d_in[2],
      (const float*)d_in[3],  (const float*)d_in[4],  (const float*)d_in[5],
      (const float*)d_in[6],  (const float*)d_in[7],  (const float*)d_in[8],
      (const float*)d_in[9],  (const float*)d_in[10], (const float*)d_in[11],
      (const float*)d_in[12], (const float*)d_in[13], (const float*)d_in[14],
      (const int*)d_in[15],   (float*)d_out);
}

// Round 14
// 746.614 us; speedup vs baseline: 2.1872x; 2.1872x over previous
//
#include <hip/hip_runtime.h>
#include <cmath>

// EVRP solver rollout — one block per batch element, 128-step decode on-device.
// PRNG: JAX threefry2x32 partitionable scheme (verified). Discrete state path
// (fuel/time/demand/mask) is bit-exact vs jnp f32; logit path is analog.
// R14 = R9 verbatim (747.8us, best). R10-R13 established: any unroll/pin
// perturbation tips the 192-reg pinned weight set over the 256-VGPR cliff
// into scratch (2.4-4.3GB re-streaming). Do not touch unrolls or pins.
#define BSZ 256
#define SEQN 256
#define HD 128
#define NEGV -1000000000.0f
#define TINYF 1.17549435e-38f
#define LOG2E 1.4426950408889634f
#define LN2F 0.6931471805599453f
#define K2L 2.885390081777927f

typedef float v2f __attribute__((ext_vector_type(2)));

static __device__ __forceinline__ v2f mk2(float a, float b) {
  v2f r; r.x = a; r.y = b; return r;
}
static __device__ __forceinline__ v2f fma2(v2f a, v2f b, v2f c) {
  return __builtin_elementwise_fma(a, b, c);
}

// DPP lane ops (VALU pipe — not LDS). quad_perm 0xB1=xor1, 0x4E=xor2, 0x1B=xor3.
#define DPPF(x, c) __int_as_float(__builtin_amdgcn_update_dpp(0, __float_as_int(x), (c), 0xF, 0xF, true))
#define DPPI(x, c) __builtin_amdgcn_update_dpp(0, (x), (c), 0xF, 0xF, true)
#define SWZF(x, p) __int_as_float(__builtin_amdgcn_ds_swizzle(__float_as_int(x), (p)))

static __device__ __forceinline__ void tf2x32(unsigned k0, unsigned k1,
                                              unsigned x0, unsigned x1,
                                              unsigned &o0, unsigned &o1) {
  unsigned ks2 = k0 ^ k1 ^ 0x1BD11BDAu;
#define TFR(r) { x0 += x1; x1 = (x1 << (r)) | (x1 >> (32 - (r))); x1 ^= x0; }
  x0 += k0; x1 += k1;
  TFR(13) TFR(15) TFR(26) TFR(6)
  x0 += k1; x1 += ks2 + 1u;
  TFR(17) TFR(29) TFR(16) TFR(24)
  x0 += ks2; x1 += k0 + 2u;
  TFR(13) TFR(15) TFR(26) TFR(6)
  x0 += k0; x1 += k1 + 3u;
  TFR(17) TFR(29) TFR(16) TFR(24)
  x0 += k1; x1 += ks2 + 4u;
  TFR(13) TFR(15) TFR(26) TFR(6)
  x0 += ks2; x1 += k0 + 5u;
#undef TFR
  o0 = x0; o1 = x1;
}

static __device__ __forceinline__ float fast_tanh(float x) {
  float y = __fmul_rn(x, K2L);
  float ay = __int_as_float(__float_as_int(y) | 0x80000000u); // -|y|
  float q = __builtin_amdgcn_exp2f(ay);
  float r = __fmul_rn(__fsub_rn(1.0f, q),
                      __builtin_amdgcn_rcpf(__fadd_rn(1.0f, q)));
  unsigned sgn = (unsigned)__float_as_int(x) & 0x80000000u;
  return __int_as_float(__float_as_int(r) | sgn);
}

static __device__ __forceinline__ float fast_sig(float x) {
  float q = __builtin_amdgcn_exp2f(__fmul_rn(x, -LOG2E));
  return __builtin_amdgcn_rcpf(__fadd_rn(1.0f, q));
}

static __device__ __forceinline__ float fast_ln(float x) {
  return __fmul_rn(__builtin_amdgcn_logf(x), LN2F);
}

__global__ __launch_bounds__(512, 2) void evrp_kernel(
    const float* __restrict__ statc, const float* __restrict__ dyn,
    const float* __restrict__ dist,  const float* __restrict__ W_s,
    const float* __restrict__ b_s,   const float* __restrict__ W_d,
    const float* __restrict__ b_d,   const float* __restrict__ W_i,
    const float* __restrict__ W_h,   const float* __restrict__ b_i,
    const float* __restrict__ b_h,   const float* __restrict__ W_att,
    const float* __restrict__ v_att, const float* __restrict__ W_c,
    const float* __restrict__ b_c,   const int* __restrict__ steps_p,
    float* __restrict__ out) {
  const int b = blockIdx.x;
  const int tid = threadIdx.x;
  const int T = steps_p[0];
  const int lane = tid & 63;
  const int wv = tid >> 6;
  const int s = tid >> 1, hf = tid & 1;      // E/FG mapping
  const int cq = tid >> 2, g = tid & 3;      // AB/C mapping

  extern __shared__ __align__(16) float4 Pdyn[];   // sP: [16 chunks][512] = 128KB

  __shared__ __align__(16) float  B0a[HD], B1a[HD], A2a[HD];
  __shared__ __align__(16) float  Ct[HD], Vt[HD];   // Ct holds sC per step
  __shared__ __align__(16) float  hstm[HD], hlm[HD], wc2v[HD];
  __shared__ __align__(16) float  A0a[HD], A1a[HD], D0a[HD];
  __shared__ __align__(16) float  C0a[HD], C1a[HD], C2a[HD], bca[HD];
  __shared__ __align__(16) float2 xy2[SEQN];
  __shared__ __align__(16) float  drowX[SEQN];
  __shared__ __align__(16) unsigned kAs[256], kBs[256];
  __shared__ __align__(16) float ws0[HD], ws1[HD], bsv[HD];
  __shared__ __align__(16) float wd0[HD], wd1[HD], wd2[HD], bdv[HD];
  __shared__ __align__(16) float2 wredA[8];   // {av, (float)ai}
  __shared__ __align__(16) float4 wredB[8];   // {S, px, py, -}

  const float* distb = dist + (size_t)b * SEQN * SEQN;

  // ---------------- prologue: loads ----------------
  if (tid < HD) {
    ws0[tid] = W_s[2 * tid]; ws1[tid] = W_s[2 * tid + 1]; bsv[tid] = b_s[tid];
    wd0[tid] = W_d[3 * tid]; wd1[tid] = W_d[3 * tid + 1]; wd2[tid] = W_d[3 * tid + 2];
    bdv[tid] = b_d[tid]; bca[tid] = b_c[tid];
    hstm[tid] = 0.0f;
  }
  float xreg = statc[b * 2 * SEQN + s];
  float yreg = statc[b * 2 * SEQN + SEQN + s];
  float demreg = dyn[b * 3 * SEQN + 2 * SEQN + s];
  float d2dR = distb[(size_t)s * SEQN];
  float dbaR;
  {
    float d10 = distb[1 * SEQN + 0], d20 = distb[2 * SEQN + 0], d30 = distb[3 * SEQN + 0];
    float d1s = distb[1 * SEQN + s], d2s = distb[2 * SEQN + s], d3s = distb[3 * SEQN + s];
    float m = fminf(fminf(__fadd_rn(d10, d1s), __fadd_rn(d20, d2s)), __fadd_rn(d30, d3s));
    dbaR = (s == 0) ? 0.0f : m;
  }
  float dnextR = distb[s];       // row 0 — fills drowX at E_0
  if (hf == 0) xy2[s] = make_float2(xreg, yreg);
  float fuelR = dyn[b * 3 * SEQN + 0];
  float timeR = dyn[b * 3 * SEQN + SEQN + 0];
  float cstR = 0.0f;
  int niR = 0;
  for (int tt = tid; tt < 256; tt += 512) {
    unsigned a0, a1; tf2x32(0u, 1u, 0u, (unsigned)tt, a0, a1);
    kAs[tt] = a0; kBs[tt] = a1;
  }
  __syncthreads();

  // ---------------- prologue: folds + register weights ----------------
  if (tid < HD) {
    int k = tid;
    const float* row = W_att + (size_t)k * 384;
    float B0 = 0, B1 = 0, B2 = 0, A0 = 0, A1 = 0, A2 = 0, A3 = 0;
    for (int c = 0; c < HD; ++c) {
      float w1 = row[c], w2 = row[128 + c];
      B0 = fmaf(w1, ws0[c], B0); B1 = fmaf(w1, ws1[c], B1); B2 = fmaf(w1, bsv[c], B2);
      A0 = fmaf(w2, wd0[c], A0); A1 = fmaf(w2, wd1[c], A1);
      A2 = fmaf(w2, wd2[c], A2); A3 = fmaf(w2, bdv[c], A3);
    }
    B0a[k] = B0; B1a[k] = B1; A2a[k] = A2; Vt[k] = v_att[k];
    A0a[k] = A0; A1a[k] = A1; D0a[k] = __fadd_rn(B2, A3);
  } else if (tid < 2 * HD) {
    int o = tid - HD;
    const float* row = W_c + (size_t)o * 256;
    float C0 = 0, C1 = 0, C2 = 0;
    for (int c = 0; c < HD; ++c) {
      float w = row[c];
      C0 = fmaf(w, ws0[c], C0); C1 = fmaf(w, ws1[c], C1); C2 = fmaf(w, bsv[c], C2);
    }
    C0a[o] = C0; C1a[o] = C1; C2a[o] = C2;
  }
  float gp0 = 0, gp1 = 0, gp2 = 0, gpw;
  {
    int j = g * HD + cq;
    const float* row = W_i + (size_t)j * HD;
    for (int c = 0; c < HD; ++c) {
      float w = row[c];
      gp0 = fmaf(w, ws0[c], gp0); gp1 = fmaf(w, ws1[c], gp1); gp2 = fmaf(w, bsv[c], gp2);
    }
    gpw = __fadd_rn(b_i[j], b_h[j]);
  }
  // register-resident weights as v2f pairs — loaded once, then made OPAQUE
  // (empty asm, value-preserving) so the allocator cannot stream them.
  v2f whreg2[HD / 2];
  {
    int j = g * HD + cq;
#pragma unroll
    for (int c2 = 0; c2 < HD / 2; ++c2)
      whreg2[c2] = *(const v2f*)(&W_h[(size_t)j * HD + 2 * c2]);
  }
  v2f wah2[16], wc22[16];
#pragma unroll
  for (int i = 0; i < 16; ++i) {
    wah2[i] = *(const v2f*)(&W_att[(size_t)cq * 384 + 256 + g * 32 + 2 * i]);
    wc22[i] = *(const v2f*)(&W_c[(size_t)cq * 256 + HD + g * 32 + 2 * i]);
  }
#pragma unroll
  for (int c = 0; c < HD / 2; c += 2)
    asm volatile("" : "+v"(whreg2[c]), "+v"(whreg2[c + 1]));
#pragma unroll
  for (int i = 0; i < 16; i += 2) {
    asm volatile("" : "+v"(wah2[i]), "+v"(wah2[i + 1]));
    asm volatile("" : "+v"(wc22[i]), "+v"(wc22[i + 1]));
  }
  __syncthreads();

  // ---------------- prologue: fill sP[s][k] = exp2(K2L*P) (rollout-constant)
  for (int idx = tid; idx < SEQN * HD; idx += 512) {
    int ss = idx >> 7, k = idx & 127;
    float2 pxy = xy2[ss];
    float dm = dyn[b * 3 * SEQN + 2 * SEQN + ss];
    float pv = fmaf(B0a[k], pxy.x, fmaf(B1a[k], pxy.y, __fmul_rn(A2a[k], dm)));
    ((float*)Pdyn)[(((k >> 2) & 15) << 11) + ((ss * 2 + (k >> 6)) << 2) + (k & 3)] =
        __builtin_amdgcn_exp2f(__fmul_rn(pv, K2L));
  }
  // Vsum = sum of v_att (folds the "+1" of tanh identity); uniform all threads
  float Vsum = 0.0f;
#pragma unroll
  for (int i = 0; i < 32; ++i) {
    float4 v4 = ((const float4*)Vt)[i];
    Vsum = __fadd_rn(Vsum, __fadd_rn(__fadd_rn(v4.x, v4.y), __fadd_rn(v4.z, v4.w)));
  }
  __syncthreads();

  float decxR = xy2[0].x, decyR = xy2[0].y;

  float* out_probs = out;
  float* out_tours = out + (size_t)BSZ * T * SEQN;
  float* out_logps = out_tours + (size_t)BSZ * T;

  const float4* Pp = Pdyn + (s * 2 + hf);   // + chunk*512
  const float* CtH = Ct + hf * 64;
  const float* VtH = Vt + hf * 64;

  float prevPr = 0.0f, prevLp = 0.0f;
  int prevNi = 0;

  // ---------------- decode loop (4 barriers/step) ----------------
  for (int t = 0; t < T; ++t) {
    // ---- top: issue prev-step stores + this step's distance-row gather ----
    if (t > 0) {
      if (hf == 0) out_probs[((size_t)b * T + (t - 1)) * SEQN + s] = prevPr;
      if (s == prevNi && hf == 0) {
        out_tours[(size_t)b * T + (t - 1)] = (float)prevNi;
        out_logps[(size_t)b * T + (t - 1)] = prevLp;
      }
      dnextR = distb[(size_t)niR * SEQN + s];
    }
    // ---- AB: gates + LSTM via quad DPP exchange; 4 acc chains ---- [(cq,g)]
    {
      v2f mA0 = mk2(0.f, 0.f), mB0 = mk2(0.f, 0.f);
      v2f mA1 = mk2(0.f, 0.f), mB1 = mk2(0.f, 0.f);
      const float4* h4 = (const float4*)hstm;
#pragma unroll
      for (int c8 = 0; c8 < HD / 8; ++c8) {
        float4 h0 = h4[2 * c8], h1 = h4[2 * c8 + 1];
        mA0 = fma2(whreg2[4 * c8 + 0], mk2(h0.x, h0.y), mA0);
        mB0 = fma2(whreg2[4 * c8 + 1], mk2(h0.z, h0.w), mB0);
        mA1 = fma2(whreg2[4 * c8 + 2], mk2(h1.x, h1.y), mA1);
        mB1 = fma2(whreg2[4 * c8 + 3], mk2(h1.z, h1.w), mB1);
      }
      float md = fmaf(gp0, decxR, fmaf(gp1, decyR, gp2));
      float mh = __fadd_rn(
          __fadd_rn(__fadd_rn(mA0.x, mA0.y), __fadd_rn(mB0.x, mB0.y)),
          __fadd_rn(__fadd_rn(mA1.x, mA1.y), __fadd_rn(mB1.x, mB1.y)));
      float V = __fadd_rn(__fadd_rn(md, mh), gpw);
      float sg = fast_sig(V), th = fast_tanh(V);
      float q = (g == 2) ? th : sg;
      float u1 = DPPF(q, 0xB1);
      float u2 = DPPF(q, 0x4E);
      float u3 = DPPF(q, 0x1B);
      float qi = (g == 0) ? q  : (g == 1) ? u1 : (g == 2) ? u2 : u3;
      float qf = (g == 0) ? u1 : (g == 1) ? q  : (g == 2) ? u3 : u2;
      float qg = (g == 0) ? u2 : (g == 1) ? u3 : (g == 2) ? q  : u1;
      float qo = (g == 0) ? u3 : (g == 1) ? u2 : (g == 2) ? u1 : q;
      float cn = __fadd_rn(__fmul_rn(qf, cstR), __fmul_rn(qi, qg));
      cstR = cn;
      float hv = __fmul_rn(qo, fast_tanh(cn));
      if (g == 0) hlm[(cq & 96) | ((cq & 31) ^ ((cq >> 5) << 3))] = hv;
    }
    __syncthreads();                               // b1
    // ---- C: W_att_h@h, W_c2@h; quad DPP reduce; write sC into Ct ---- [(cq,g)]
    {
      v2f pwA = mk2(0.f, 0.f), pwB = mk2(0.f, 0.f);
      v2f pcA = mk2(0.f, 0.f), pcB = mk2(0.f, 0.f);
      const float4* hl4 = (const float4*)hlm;
#pragma unroll
      for (int l4 = 0; l4 < 8; ++l4) {
        float4 hh = hl4[(g << 3) + (l4 ^ (g << 1))];   // XOR-swizzled, conflict-free
        v2f hA = mk2(hh.x, hh.y), hB = mk2(hh.z, hh.w);
        pwA = fma2(wah2[2 * l4],     hA, pwA);
        pwB = fma2(wah2[2 * l4 + 1], hB, pwB);
        pcA = fma2(wc22[2 * l4],     hA, pcA);
        pcB = fma2(wc22[2 * l4 + 1], hB, pcB);
      }
      float pw = __fadd_rn(__fadd_rn(pwA.x, pwA.y), __fadd_rn(pwB.x, pwB.y));
      float pc = __fadd_rn(__fadd_rn(pcA.x, pcA.y), __fadd_rn(pcB.x, pcB.y));
      pw = __fadd_rn(pw, DPPF(pw, 0xB1));
      pc = __fadd_rn(pc, DPPF(pc, 0xB1));
      pw = __fadd_rn(pw, DPPF(pw, 0x4E));
      pc = __fadd_rn(pc, DPPF(pc, 0x4E));
      if (g == 0) {
        wc2v[cq] = pc;
        float Ck = fmaf(A0a[cq], fuelR, fmaf(A1a[cq], timeR, __fadd_rn(D0a[cq], pw)));
        Ct[cq] = __builtin_amdgcn_exp2f(__fmul_rn(Ck, K2L));   // sC
      }
    }
    __syncthreads();                               // b2
    // ---- E: mask, drow fill, rcp loop (no exp), gumbel, DPP-reduce ----
    float pe, lg;
    if (hf == 0) drowX[s] = dnextR;   // row of node niR (prev step's pick)
    bool mk;
    if (t == 0) mk = true;
    else {
      bool fok = fuelR >= __fmul_rn(0.2f, __fadd_rn(dnextR, dbaR));
      bool tok = timeR >= __fdiv_rn(__fadd_rn(dnextR, d2dR), 60.0f);
      bool cust = (demreg > 0.0f) && fok && tok;
      mk = (s <= 3) ? (s != niR) : cust;
      if (s == 0) mk = true;
    }
    {
      unsigned rb;
      { unsigned o0, o1; tf2x32(kAs[t], kBs[t], 0u, (unsigned)(b * SEQN + s), o0, o1); rb = o0 ^ o1; }
      float f = __uint_as_float((rb >> 9) | 0x3f800000u) - 1.0f;
      float u = fmaxf(TINYF, __fadd_rn(f, TINYF));
      float gmb = -fast_ln(-fast_ln(u));
      const v2f one2 = mk2(1.0f, 1.0f);
      v2f a0 = mk2(0.f, 0.f), a1 = mk2(0.f, 0.f);
      v2f a2 = mk2(0.f, 0.f), a3 = mk2(0.f, 0.f);
#pragma unroll
      for (int i = 0; i < 8; ++i) {
        // even group 2i → chains a0,a1; odd group 2i+1 → chains a2,a3
        float4 pv0 = Pp[(2 * i) << 9];
        float4 ct0 = *(const float4*)(CtH + 8 * i);
        float4 vv0 = *(const float4*)(VtH + 8 * i);
        v2f sA = mk2(pv0.x, pv0.y) * mk2(ct0.x, ct0.y) + one2;
        v2f sB = mk2(pv0.z, pv0.w) * mk2(ct0.z, ct0.w) + one2;
        v2f rA, rB;
        rA.x = __builtin_amdgcn_rcpf(sA.x); rA.y = __builtin_amdgcn_rcpf(sA.y);
        rB.x = __builtin_amdgcn_rcpf(sB.x); rB.y = __builtin_amdgcn_rcpf(sB.y);
        a0 = fma2(mk2(vv0.x, vv0.y), rA, a0);
        a1 = fma2(mk2(vv0.z, vv0.w), rB, a1);
        float4 pv1 = Pp[(2 * i + 1) << 9];
        float4 ct1 = *(const float4*)(CtH + 8 * i + 4);
        float4 vv1 = *(const float4*)(VtH + 8 * i + 4);
        v2f sC = mk2(pv1.x, pv1.y) * mk2(ct1.x, ct1.y) + one2;
        v2f sD = mk2(pv1.z, pv1.w) * mk2(ct1.z, ct1.w) + one2;
        v2f rC, rD;
        rC.x = __builtin_amdgcn_rcpf(sC.x); rC.y = __builtin_amdgcn_rcpf(sC.y);
        rD.x = __builtin_amdgcn_rcpf(sD.x); rD.y = __builtin_amdgcn_rcpf(sD.y);
        a2 = fma2(mk2(vv1.x, vv1.y), rC, a2);
        a3 = fma2(mk2(vv1.z, vv1.w), rD, a3);
      }
      v2f t01 = a0 + a1, t23 = a2 + a3;
      v2f tt = t01 + t23;
      float part = __fadd_rn(tt.x, tt.y);
      float tot = __fadd_rn(part, DPPF(part, 0xB1));   // both halves
      float e = fmaf(-2.0f, tot, Vsum);                // Σv·tanh = Σv − 2Σv/(s+1)
      lg = mk ? e : NEGV;
      pe = __builtin_amdgcn_exp2f(__fmul_rn(lg, LOG2E));
      float sc = __fadd_rn(gmb, lg);
      float av = sc; int ai = s;
      float S = pe, px = __fmul_rn(pe, xreg), py = __fmul_rn(pe, yreg);
      {
        float ov = DPPF(av, 0x4E); int oi = DPPI(ai, 0x4E);
        if (ov > av || (ov == av && oi < ai)) { av = ov; ai = oi; }
        S  = __fadd_rn(S,  DPPF(S,  0x4E));
        px = __fadd_rn(px, DPPF(px, 0x4E));
        py = __fadd_rn(py, DPPF(py, 0x4E));
      }
      {
        float ov = DPPF(av, 0x124); int oi = DPPI(ai, 0x124);
        if (ov > av || (ov == av && oi < ai)) { av = ov; ai = oi; }
        S  = __fadd_rn(S,  DPPF(S,  0x124));
        px = __fadd_rn(px, DPPF(px, 0x124));
        py = __fadd_rn(py, DPPF(py, 0x124));
      }
      {
        float ov = DPPF(av, 0x128); int oi = DPPI(ai, 0x128);
        if (ov > av || (ov == av && oi < ai)) { av = ov; ai = oi; }
        S  = __fadd_rn(S,  DPPF(S,  0x128));
        px = __fadd_rn(px, DPPF(px, 0x128));
        py = __fadd_rn(py, DPPF(py, 0x128));
      }
      {
        float ov = SWZF(av, 0x401F); int oi = __builtin_amdgcn_ds_swizzle(ai, 0x401F);
        if (ov > av || (ov == av && oi < ai)) { av = ov; ai = oi; }
        S  = __fadd_rn(S,  SWZF(S,  0x401F));
        px = __fadd_rn(px, SWZF(px, 0x401F));
        py = __fadd_rn(py, SWZF(py, 0x401F));
      }
      {
        float ov = __shfl_xor(av, 32, 64); int oi = __shfl_xor(ai, 32, 64);
        if (ov > av || (ov == av && oi < ai)) { av = ov; ai = oi; }
        S  = __fadd_rn(S,  __shfl_xor(S,  32, 64));
        px = __fadd_rn(px, __shfl_xor(px, 32, 64));
        py = __fadd_rn(py, __shfl_xor(py, 32, 64));
      }
      if (lane == 0) {
        wredA[wv] = make_float2(av, (float)ai);
        wredB[wv] = make_float4(S, px, py, 0.0f);
      }
    }
    __syncthreads();                               // b3
    // ---- FG: packed final combine, state update, h_new ----
    {
      float2 a0c = wredA[0];
      float bv = a0c.x; int bi = (int)a0c.y;
#pragma unroll
      for (int w = 1; w < 8; ++w) {
        float2 aw = wredA[w];
        if (aw.x > bv) { bv = aw.x; bi = (int)aw.y; }
      }
      int ni = bi;
      float4 b0 = wredB[0];
      float S = b0.x, px = b0.y, py = b0.z;
#pragma unroll
      for (int w = 1; w < 8; ++w) {
        float4 bw = wredB[w];
        S = __fadd_rn(S, bw.x); px = __fadd_rn(px, bw.y); py = __fadd_rn(py, bw.z);
      }
      float dis = drowX[ni];
      float fl = __fsub_rn(fuelR, __fmul_rn(0.2f, dis));
      float tm = __fsub_rn(timeR, __fdiv_rn(dis, 60.0f));
      if (ni <= 3) fl = 60.0f;
      if (ni == 0) tm = 11.0f;
      fuelR = fl; timeR = tm;
      if (s == ni && ni > 3) demreg = 0.0f;
      float2 dxy = xy2[ni];
      decxR = dxy.x; decyR = dxy.y;
      prevPr = __fdiv_rn(pe, S);
      prevLp = __fsub_rn(lg, fast_ln(S));
      prevNi = ni;
      if (tid < HD) {
        float cx = __fdiv_rn(px, S), cy = __fdiv_rn(py, S);
        float ctxd = fmaf(C0a[tid], cx, fmaf(C1a[tid], cy, C2a[tid]));
        float val = __fadd_rn(__fadd_rn(ctxd, wc2v[tid]), bca[tid]);
        hstm[tid] = fast_tanh(val);
      }
      niR = ni;
    }
    __syncthreads();                               // b4
  }
  // final step's outputs
  if (hf == 0) out_probs[((size_t)b * T + (T - 1)) * SEQN + s] = prevPr;
  if (s == prevNi && hf == 0) {
    out_tours[(size_t)b * T + (T - 1)] = (float)prevNi;
    out_logps[(size_t)b * T + (T - 1)] = prevLp;
  }
}

extern "C" void kernel_launch(void* const* d_in, const int* in_sizes, int n_in,
                              void* d_out, int out_size, void* d_ws, size_t ws_size,
                              hipStream_t stream) {
  (void)in_sizes; (void)n_in; (void)out_size; (void)d_ws; (void)ws_size;
  (void)hipFuncSetAttribute((const void*)evrp_kernel,
                            hipFuncAttributeMaxDynamicSharedMemorySize,
                            SEQN * HD * 4);
  evrp_kernel<<<dim3(BSZ), dim3(512), SEQN * HD * 4, stream>>>(
      (const float*)d_in[0],  (const float*)d_in[1],  (const float*)d_in[2],
      (const float*)d_in[3],  (const float*)d_in[4],  (const float*)d_in[5],
      (const float*)d_in[6],  (const float*)d_in[7],  (const float*)d_in[8],
      (const float*)d_in[9],  (const float*)d_in[10], (const float*)d_in[11],
      (const float*)d_in[12], (const float*)d_in[13], (const float*)d_in[14],
      (const int*)d_in[15],   (float*)d_out);
}